// Round 1
// baseline (57499.170 us; speedup 1.0000x reference)
//
#include <hip/hip_runtime.h>

#define N_NODES 1024
#define B_SZ    64
#define T_STEPS 12
#define H_DIM   64
#define CI      65
#define KC      130
#define JW      (B_SZ*CI)   // 4160

// ---------------- A = softmax(relu(E E^T), axis=1) ----------------
__global__ __launch_bounds__(256) void k_supports(const float* __restrict__ E,
                                                  float* __restrict__ A) {
    int n = blockIdx.x;
    int tid = threadIdx.x;
    __shared__ float en[16];
    __shared__ float red[256];
    if (tid < 16) en[tid] = E[n*16 + tid];
    __syncthreads();
    float s[4];
    float mx = -1e30f;
#pragma unroll
    for (int i = 0; i < 4; i++) {
        int m = tid + i*256;
        float acc = 0.f;
#pragma unroll
        for (int d = 0; d < 16; d++) acc += en[d]*E[m*16 + d];
        acc = fmaxf(acc, 0.f);
        s[i] = acc;
        mx = fmaxf(mx, acc);
    }
    red[tid] = mx; __syncthreads();
    for (int st = 128; st > 0; st >>= 1) {
        if (tid < st) red[tid] = fmaxf(red[tid], red[tid+st]);
        __syncthreads();
    }
    mx = red[0]; __syncthreads();
    float sum = 0.f;
#pragma unroll
    for (int i = 0; i < 4; i++) { s[i] = expf(s[i]-mx); sum += s[i]; }
    red[tid] = sum; __syncthreads();
    for (int st = 128; st > 0; st >>= 1) {
        if (tid < st) red[tid] += red[tid+st];
        __syncthreads();
    }
    float inv = 1.f / red[0];
#pragma unroll
    for (int i = 0; i < 4; i++) A[(size_t)n*1024 + tid + i*256] = s[i]*inv;
}

// ---------------- Wout[n, idx] = sum_d E[n,d] * Win[d, idx] ----------------
__global__ __launch_bounds__(256) void k_mix(const float* __restrict__ E,
                                             const float* __restrict__ Win,
                                             float* __restrict__ Wout, int SZ) {
    int idx = blockIdx.x*256 + threadIdx.x;
    if (idx >= SZ) return;
    float w[16];
#pragma unroll
    for (int d = 0; d < 16; d++) w[d] = Win[(size_t)d*SZ + idx];
    int n0 = blockIdx.y * 32;
    for (int n = n0; n < n0+32; n++) {
        float acc = 0.f;
#pragma unroll
        for (int d = 0; d < 16; d++) acc += E[n*16 + d]*w[d];
        Wout[(size_t)n*SZ + idx] = acc;
    }
}

// ---------------- XS init: xt = src[b,0,n], h = 0 ----------------
__global__ __launch_bounds__(256) void k_init_xs(const float* __restrict__ s,
                                                 float* __restrict__ XS) {
    int i = blockIdx.x*256 + threadIdx.x;   // over N*B*CI = 4,259,840 exactly
    int c  = i % CI;
    int nb = i / CI;
    int b  = nb & 63;
    int n  = nb >> 6;
    XS[i] = (c == 0) ? s[((size_t)b*T_STEPS)*N_NODES + n] : 0.f;
}

// ---------------- graph conv: C[n][j] = sum_m A[n][m] X[m][j] ----------------
// block tile 128 rows x 64 cols, K-chunk 16. grid (65, 8), 256 threads.
__global__ __launch_bounds__(256) void k_gemm(const float* __restrict__ A,
                                              const float* __restrict__ X,
                                              float* __restrict__ C) {
    __shared__ float At[16][132];
    __shared__ float Xt[16][68];
    int tid = threadIdx.x;
    int ty = tid >> 4, tx = tid & 15;
    int n0 = blockIdx.y * 128;
    int j0 = blockIdx.x * 64;
    float acc[8][4];
#pragma unroll
    for (int i = 0; i < 8; i++)
#pragma unroll
        for (int j = 0; j < 4; j++) acc[i][j] = 0.f;

    for (int kc = 0; kc < 1024; kc += 16) {
#pragma unroll
        for (int l = 0; l < 8; l++) {
            int e = tid + l*256;          // 0..2047
            int r = e >> 4, kk = e & 15;
            At[kk][r] = A[(size_t)(n0 + r)*1024 + kc + kk];
        }
#pragma unroll
        for (int l = 0; l < 4; l++) {
            int e = tid + l*256;          // 0..1023
            int kk = e >> 6, j = e & 63;
            Xt[kk][j] = X[(size_t)(kc + kk)*JW + j0 + j];
        }
        __syncthreads();
#pragma unroll
        for (int kk = 0; kk < 16; kk++) {
            float a[8], b[4];
#pragma unroll
            for (int i = 0; i < 8; i++) a[i] = At[kk][ty*8 + i];
#pragma unroll
            for (int j = 0; j < 4; j++) b[j] = Xt[kk][tx*4 + j];
#pragma unroll
            for (int i = 0; i < 8; i++)
#pragma unroll
                for (int j = 0; j < 4; j++) acc[i][j] += a[i]*b[j];
        }
        __syncthreads();
    }
#pragma unroll
    for (int i = 0; i < 8; i++) {
        float4 v = make_float4(acc[i][0], acc[i][1], acc[i][2], acc[i][3]);
        *reinterpret_cast<float4*>(&C[(size_t)(n0 + ty*8 + i)*JW + j0 + tx*4]) = v;
    }
}

// ---------------- gate: per node GEMM (64x130)@(130x128) + sigmoid ----------------
// writes CAND = concat(xt, z*h) and R
__global__ __launch_bounds__(256) void k_gate(const float* __restrict__ XS,
                                              const float* __restrict__ ZG,
                                              const float* __restrict__ WG,
                                              const float* __restrict__ BG,
                                              float* __restrict__ CAND,
                                              float* __restrict__ Rb) {
    int n = blockIdx.x;
    int tid = threadIdx.x;
    __shared__ float Zl[KC][68];     // [kc][b]
    __shared__ float Wl[16*128];
    for (int i = tid; i < JW; i += 256) {
        int b = i / CI, c = i % CI;
        float xv = XS[(size_t)n*JW + i];
        float zv = ZG[(size_t)n*JW + i];
        Zl[c][b] = xv;
        Zl[65 + c][b] = zv;
    }
    __syncthreads();
    int ot = tid & 15, bt = tid >> 4;
    int o0 = ot*8, b0 = bt*4;
    float acc[4][8];
#pragma unroll
    for (int i = 0; i < 4; i++)
#pragma unroll
        for (int j = 0; j < 8; j++) acc[i][j] = 0.f;

    for (int kc0 = 0; kc0 < KC; kc0 += 16) {
        int cnt = (KC - kc0 < 16) ? (KC - kc0) : 16;
        __syncthreads();
        for (int i = tid; i < cnt*128; i += 256)
            Wl[i] = WG[(size_t)(n*KC + kc0)*128 + i];
        __syncthreads();
        for (int kk = 0; kk < cnt; kk++) {
            int kc = kc0 + kk;
            float a[4], w[8];
#pragma unroll
            for (int j = 0; j < 4; j++) a[j] = Zl[kc][b0 + j];
#pragma unroll
            for (int j = 0; j < 8; j++) w[j] = Wl[kk*128 + o0 + j];
#pragma unroll
            for (int bb = 0; bb < 4; bb++)
#pragma unroll
                for (int oo = 0; oo < 8; oo++) acc[bb][oo] += a[bb]*w[oo];
        }
    }
#pragma unroll
    for (int bb = 0; bb < 4; bb++) {
        int b = b0 + bb;
#pragma unroll
        for (int oo = 0; oo < 8; oo++) {
            int o = o0 + oo;
            float v = acc[bb][oo] + BG[n*128 + o];
            v = 1.f / (1.f + expf(-v));
            if (o < 64) {
                CAND[(size_t)n*JW + b*CI + 1 + o] = v * Zl[1 + o][b];  // z * h
            } else {
                Rb[(size_t)n*4096 + b*64 + (o - 64)] = v;              // r
            }
        }
    }
    if (tid < 64) CAND[(size_t)n*JW + tid*CI] = Zl[0][tid];            // xt
}

// ---------------- up: per node GEMM (64x130)@(130x64) + tanh + h update ----------------
__global__ __launch_bounds__(256) void k_up(const float* __restrict__ CAND,
                                            const float* __restrict__ CG,
                                            const float* __restrict__ WU,
                                            const float* __restrict__ BU,
                                            const float* __restrict__ Rb,
                                            float* __restrict__ XS,
                                            const float* __restrict__ srcN,
                                            int tnext, int hasNext) {
    int n = blockIdx.x;
    int tid = threadIdx.x;
    __shared__ float Zl[KC][68];
    __shared__ float Wl[16*64];
    for (int i = tid; i < JW; i += 256) {
        int b = i / CI, c = i % CI;
        float cv = CAND[(size_t)n*JW + i];
        float gv = CG[(size_t)n*JW + i];
        Zl[c][b] = cv;
        Zl[65 + c][b] = gv;
    }
    __syncthreads();
    int ot = tid & 15, bt = tid >> 4;
    int j0 = ot*4, b0 = bt*4;
    float acc[4][4];
#pragma unroll
    for (int i = 0; i < 4; i++)
#pragma unroll
        for (int j = 0; j < 4; j++) acc[i][j] = 0.f;

    for (int kc0 = 0; kc0 < KC; kc0 += 16) {
        int cnt = (KC - kc0 < 16) ? (KC - kc0) : 16;
        __syncthreads();
        for (int i = tid; i < cnt*64; i += 256)
            Wl[i] = WU[(size_t)(n*KC + kc0)*64 + i];
        __syncthreads();
        for (int kk = 0; kk < cnt; kk++) {
            int kc = kc0 + kk;
            float a[4], w[4];
#pragma unroll
            for (int j = 0; j < 4; j++) a[j] = Zl[kc][b0 + j];
#pragma unroll
            for (int j = 0; j < 4; j++) w[j] = Wl[kk*64 + j0 + j];
#pragma unroll
            for (int bb = 0; bb < 4; bb++)
#pragma unroll
                for (int jj = 0; jj < 4; jj++) acc[bb][jj] += a[bb]*w[jj];
        }
    }
#pragma unroll
    for (int bb = 0; bb < 4; bb++) {
        int b = b0 + bb;
#pragma unroll
        for (int jj = 0; jj < 4; jj++) {
            int j = j0 + jj;
            float hc = tanhf(acc[bb][jj] + BU[n*64 + j]);
            float r  = Rb[(size_t)n*4096 + b*64 + j];
            size_t xi = (size_t)n*JW + b*CI + 1 + j;
            float hold = XS[xi];
            XS[xi] = r*hold + (1.f - r)*hc;
        }
    }
    if (hasNext && tid < 64)
        XS[(size_t)n*JW + tid*CI] = srcN[((size_t)tid*T_STEPS + tnext)*N_NODES + n];
}

// ---------------- head 1: out1 + src1, SRC2 = src - src1 ----------------
__global__ __launch_bounds__(256) void k_head1(const float* __restrict__ XS,
                                               const float* __restrict__ c1W,
                                               const float* __restrict__ c1b,
                                               const float* __restrict__ c2W,
                                               const float* __restrict__ c2b,
                                               const float* __restrict__ src,
                                               float* __restrict__ OUT1,
                                               float* __restrict__ SRC2) {
    int n = blockIdx.x, tid = threadIdx.x;
    __shared__ float Hl[64][65];
    __shared__ float w1[12][64];
    __shared__ float o1[64][13];
    for (int i = tid; i < 4096; i += 256) {
        int b = i >> 6, j = i & 63;
        Hl[b][j] = XS[(size_t)n*JW + b*CI + 1 + j];
    }
    for (int i = tid; i < 768; i += 256) w1[i >> 6][i & 63] = c1W[i];
    __syncthreads();
    int b = tid & 63, cg = tid >> 6;
#pragma unroll
    for (int cc = 0; cc < 3; cc++) {
        int c = cg*3 + cc;
        float accv = c1b[c];
        for (int j = 0; j < 64; j++) accv += Hl[b][j]*w1[c][j];
        o1[b][c] = accv;
    }
    __syncthreads();
#pragma unroll
    for (int cc = 0; cc < 3; cc++) {
        int c = cg*3 + cc;
        float s1 = c2b[c];
#pragma unroll
        for (int j = 0; j < 12; j++) s1 += o1[b][j]*c2W[c*12 + j];
        size_t idx = ((size_t)b*12 + c)*1024 + n;
        OUT1[idx] = o1[b][c];
        SRC2[idx] = src[idx] - s1;
    }
}

// ---------------- head 2: out = OUT1 + h2 . c3W + c3b ----------------
__global__ __launch_bounds__(256) void k_head2(const float* __restrict__ XS,
                                               const float* __restrict__ c3W,
                                               const float* __restrict__ c3b,
                                               const float* __restrict__ OUT1,
                                               float* __restrict__ out) {
    int n = blockIdx.x, tid = threadIdx.x;
    __shared__ float Hl[64][65];
    __shared__ float w3[12][64];
    for (int i = tid; i < 4096; i += 256) {
        int b = i >> 6, j = i & 63;
        Hl[b][j] = XS[(size_t)n*JW + b*CI + 1 + j];
    }
    for (int i = tid; i < 768; i += 256) w3[i >> 6][i & 63] = c3W[i];
    __syncthreads();
    int b = tid & 63, cg = tid >> 6;
#pragma unroll
    for (int cc = 0; cc < 3; cc++) {
        int c = cg*3 + cc;
        float accv = c3b[c];
        for (int j = 0; j < 64; j++) accv += Hl[b][j]*w3[c][j];
        size_t idx = ((size_t)b*12 + c)*1024 + n;
        out[idx] = OUT1[idx] + accv;
    }
}

extern "C" void kernel_launch(void* const* d_in, const int* in_sizes, int n_in,
                              void* d_out, int out_size, void* d_ws, size_t ws_size,
                              hipStream_t stream) {
    const float* src  = (const float*)d_in[0];
    const float* E    = (const float*)d_in[1];
    const float* e1gW = (const float*)d_in[2];
    const float* e1gb = (const float*)d_in[3];
    const float* e1uW = (const float*)d_in[4];
    const float* e1ub = (const float*)d_in[5];
    const float* e2gW = (const float*)d_in[6];
    const float* e2gb = (const float*)d_in[7];
    const float* e2uW = (const float*)d_in[8];
    const float* e2ub = (const float*)d_in[9];
    const float* c1W  = (const float*)d_in[10];
    const float* c1b  = (const float*)d_in[11];
    const float* c2W  = (const float*)d_in[12];
    const float* c2b  = (const float*)d_in[13];
    const float* c3W  = (const float*)d_in[14];
    const float* c3b  = (const float*)d_in[15];

    float* ws = (float*)d_ws;
    float* A    = ws;                    // 1,048,576
    float* WG   = A    + 1048576;        // 17,039,360
    float* WU   = WG   + 17039360;       //  8,519,680
    float* BG   = WU   + 8519680;        //    131,072
    float* BU   = BG   + 131072;         //     65,536
    float* XS   = BU   + 65536;          //  4,259,840
    float* ZG   = XS   + 4259840;        //  4,259,840  (doubles as CG)
    float* CAND = ZG   + 4259840;        //  4,259,840
    float* Rb   = CAND + 4259840;        //  4,194,304
    float* OUT1 = Rb   + 4194304;        //    786,432
    float* SRC2 = OUT1 + 786432;         //    786,432  -> total ~181 MB

    k_supports<<<N_NODES, 256, 0, stream>>>(E, A);

    auto run_encoder = [&](const float* s, const float* gW, const float* gb,
                           const float* uW, const float* ub) {
        k_mix<<<dim3(65, 32), 256, 0, stream>>>(E, gW, WG, 16640);
        k_mix<<<dim3(33, 32), 256, 0, stream>>>(E, uW, WU, 8320);
        k_mix<<<dim3(1, 32),  256, 0, stream>>>(E, gb, BG, 128);
        k_mix<<<dim3(1, 32),  256, 0, stream>>>(E, ub, BU, 64);
        k_init_xs<<<16640, 256, 0, stream>>>(s, XS);
        for (int t = 0; t < T_STEPS; t++) {
            k_gemm<<<dim3(65, 8), 256, 0, stream>>>(A, XS, ZG);
            k_gate<<<N_NODES, 256, 0, stream>>>(XS, ZG, WG, BG, CAND, Rb);
            k_gemm<<<dim3(65, 8), 256, 0, stream>>>(A, CAND, ZG);
            k_up<<<N_NODES, 256, 0, stream>>>(CAND, ZG, WU, BU, Rb, XS, s,
                                              t + 1, (t + 1 < T_STEPS) ? 1 : 0);
        }
    };

    run_encoder(src, e1gW, e1gb, e1uW, e1ub);
    k_head1<<<N_NODES, 256, 0, stream>>>(XS, c1W, c1b, c2W, c2b, src, OUT1, SRC2);
    run_encoder(SRC2, e2gW, e2gb, e2uW, e2ub);
    k_head2<<<N_NODES, 256, 0, stream>>>(XS, c3W, c3b, OUT1, (float*)d_out);
}

// Round 2
// 10672.266 us; speedup vs baseline: 5.3877x; 5.3877x over previous
//
#include <hip/hip_runtime.h>

#define N_NODES 1024
#define T_STEPS 12
#define JW2     4224          // padded column count = 33*128 (real 4160 = 65*64)
#define NELEM   (N_NODES*JW2) // 4,325,376

__device__ __forceinline__ float4 f4fma(float4 acc, float4 a, float s) {
    acc.x = fmaf(a.x, s, acc.x); acc.y = fmaf(a.y, s, acc.y);
    acc.z = fmaf(a.z, s, acc.z); acc.w = fmaf(a.w, s, acc.w);
    return acc;
}
__device__ __forceinline__ float4 f4add(float4 a, float4 b) {
    a.x += b.x; a.y += b.y; a.z += b.z; a.w += b.w; return a;
}
__device__ __forceinline__ float4 sig4(float4 v, float b) {
    float4 r;
    r.x = 1.f/(1.f+expf(-(v.x+b))); r.y = 1.f/(1.f+expf(-(v.y+b)));
    r.z = 1.f/(1.f+expf(-(v.z+b))); r.w = 1.f/(1.f+expf(-(v.w+b)));
    return r;
}
__device__ __forceinline__ float4 tanh4(float4 v, float b) {
    float4 r;
    r.x = tanhf(v.x+b); r.y = tanhf(v.y+b);
    r.z = tanhf(v.z+b); r.w = tanhf(v.w+b);
    return r;
}

// ---------------- A = softmax(relu(E E^T), axis=1) ----------------
__global__ __launch_bounds__(256) void k_supports(const float* __restrict__ E,
                                                  float* __restrict__ A) {
    int n = blockIdx.x;
    int tid = threadIdx.x;
    __shared__ float en[16];
    __shared__ float red[256];
    if (tid < 16) en[tid] = E[n*16 + tid];
    __syncthreads();
    float s[4];
    float mx = -1e30f;
#pragma unroll
    for (int i = 0; i < 4; i++) {
        int m = tid + i*256;
        float acc = 0.f;
#pragma unroll
        for (int d = 0; d < 16; d++) acc += en[d]*E[m*16 + d];
        acc = fmaxf(acc, 0.f);
        s[i] = acc;
        mx = fmaxf(mx, acc);
    }
    red[tid] = mx; __syncthreads();
    for (int st = 128; st > 0; st >>= 1) {
        if (tid < st) red[tid] = fmaxf(red[tid], red[tid+st]);
        __syncthreads();
    }
    mx = red[0]; __syncthreads();
    float sum = 0.f;
#pragma unroll
    for (int i = 0; i < 4; i++) { s[i] = expf(s[i]-mx); sum += s[i]; }
    red[tid] = sum; __syncthreads();
    for (int st = 128; st > 0; st >>= 1) {
        if (tid < st) red[tid] += red[tid+st];
        __syncthreads();
    }
    float inv = 1.f / red[0];
#pragma unroll
    for (int i = 0; i < 4; i++) A[(size_t)n*1024 + tid + i*256] = s[i]*inv;
}

// ---------------- Wout[n, idx] = sum_d E[n,d] * Win[d, idx] ----------------
__global__ __launch_bounds__(256) void k_mix(const float* __restrict__ E,
                                             const float* __restrict__ Win,
                                             float* __restrict__ Wout, int SZ) {
    int idx = blockIdx.x*256 + threadIdx.x;
    if (idx >= SZ) return;
    float w[16];
#pragma unroll
    for (int d = 0; d < 16; d++) w[d] = Win[(size_t)d*SZ + idx];
    int n0 = blockIdx.y * 32;
    for (int n = n0; n < n0+32; n++) {
        float acc = 0.f;
#pragma unroll
        for (int d = 0; d < 16; d++) acc += E[n*16 + d]*w[d];
        Wout[(size_t)n*SZ + idx] = acc;
    }
}

// ---------------- XS init (c-major layout): XS[n][c*64+b], pads zeroed ----------------
__global__ __launch_bounds__(256) void k_init_xs(const float* __restrict__ src,
                                                 float* __restrict__ XS) {
    int i = blockIdx.x*256 + threadIdx.x;   // grid covers NELEM exactly
    int col = i % JW2;
    int n   = i / JW2;
    float v = 0.f;
    if (col < 64) v = src[((size_t)col*T_STEPS)*N_NODES + n];  // c==0 row: xt(b=col)
    XS[i] = v;
}

// ---------------- graph conv: C[n][col] = sum_m A[n][m] X[m][col] ----------------
// 128x128 tile, 256 threads, per-thread 8x8 (2x2 blocks of 4). KL = K-range length.
__global__ __launch_bounds__(256, 2) void k_gemm(const float* __restrict__ A,
                                                 const float* __restrict__ X,
                                                 float* __restrict__ C, int KL) {
    __shared__ float As[16][132];   // [kk][m] (transposed A tile)
    __shared__ float Xs[16][132];   // [kk][j]
    int tid = threadIdx.x;
    int tx = tid & 15, ty = tid >> 4;
    int tx4 = tx*4, ty4 = ty*4;
    int n0 = blockIdx.y * 128;
    int j0 = blockIdx.x * 128;
    int kc0 = blockIdx.z * KL;
    int arow = tid >> 1, ach = (tid & 1) * 8;
    int xkk = tid >> 4, xjj = (tid & 15) * 8;

    float4 acc[2][2][4];
#pragma unroll
    for (int a = 0; a < 2; a++)
#pragma unroll
        for (int b = 0; b < 2; b++)
#pragma unroll
            for (int r = 0; r < 4; r++) acc[a][b][r] = make_float4(0.f,0.f,0.f,0.f);

    for (int kc = kc0; kc < kc0 + KL; kc += 16) {
        float4 av0 = *(const float4*)&A[(size_t)(n0+arow)*1024 + kc + ach];
        float4 av1 = *(const float4*)&A[(size_t)(n0+arow)*1024 + kc + ach + 4];
        float4 xv0 = *(const float4*)&X[(size_t)(kc+xkk)*JW2 + j0 + xjj];
        float4 xv1 = *(const float4*)&X[(size_t)(kc+xkk)*JW2 + j0 + xjj + 4];
        __syncthreads();
        As[ach+0][arow] = av0.x; As[ach+1][arow] = av0.y;
        As[ach+2][arow] = av0.z; As[ach+3][arow] = av0.w;
        As[ach+4][arow] = av1.x; As[ach+5][arow] = av1.y;
        As[ach+6][arow] = av1.z; As[ach+7][arow] = av1.w;
        *(float4*)&Xs[xkk][xjj]   = xv0;
        *(float4*)&Xs[xkk][xjj+4] = xv1;
        __syncthreads();
#pragma unroll
        for (int kk = 0; kk < 16; kk++) {
            float4 a0 = *(float4*)&As[kk][ty4];
            float4 a1 = *(float4*)&As[kk][64+ty4];
            float4 b0 = *(float4*)&Xs[kk][tx4];
            float4 b1 = *(float4*)&Xs[kk][64+tx4];
            float aa0[4] = {a0.x,a0.y,a0.z,a0.w};
            float aa1[4] = {a1.x,a1.y,a1.z,a1.w};
#pragma unroll
            for (int r = 0; r < 4; r++) {
                acc[0][0][r] = f4fma(acc[0][0][r], b0, aa0[r]);
                acc[0][1][r] = f4fma(acc[0][1][r], b1, aa0[r]);
                acc[1][0][r] = f4fma(acc[1][0][r], b0, aa1[r]);
                acc[1][1][r] = f4fma(acc[1][1][r], b1, aa1[r]);
            }
        }
    }
#pragma unroll
    for (int a = 0; a < 2; a++)
#pragma unroll
        for (int r = 0; r < 4; r++) {
            int row = n0 + a*64 + ty4 + r;
#pragma unroll
            for (int b = 0; b < 2; b++)
                *(float4*)&C[(size_t)row*JW2 + j0 + b*64 + tx4] = acc[a][b][r];
        }
}

// ---------------- gate: per-node GEMM (64b x 130kc)@(130 x 128) + sigmoid ----------------
// Zl rows 0..64 = xs (xt;h), rows 65..129 = A@xs. Writes CAND=(xt; z*h), Rb=r.
__global__ __launch_bounds__(256) void k_gate(const float* __restrict__ XS,
                                              const float* __restrict__ ZG0,
                                              const float* __restrict__ ZG1,
                                              int split,
                                              const float* __restrict__ WG,
                                              const float* __restrict__ BG,
                                              float* __restrict__ CAND,
                                              float* __restrict__ Rb) {
    int n = blockIdx.x, tid = threadIdx.x;
    __shared__ float Zl[130*64];
    __shared__ float Wl[16*128];
    {
        const float4* xs4 = (const float4*)(XS + (size_t)n*JW2);
        const float4* z04 = (const float4*)(ZG0 + (size_t)n*JW2);
        const float4* z14 = (const float4*)(ZG1 + (size_t)n*JW2);
        float4* zl4 = (float4*)Zl;
        for (int i = tid; i < 1040; i += 256) zl4[i] = xs4[i];
        for (int i = tid; i < 1040; i += 256) {
            float4 v = z04[i];
            if (split) v = f4add(v, z14[i]);
            zl4[1040 + i] = v;
        }
    }
    int jt = tid & 15, bt = tid >> 4;
    int j0 = jt*4, b0 = bt*4;
    float4 accz[4], accr[4];
#pragma unroll
    for (int i = 0; i < 4; i++) { accz[i] = make_float4(0,0,0,0); accr[i] = make_float4(0,0,0,0); }

    for (int kc0 = 0; kc0 < 130; kc0 += 16) {
        int cnt = (130 - kc0 < 16) ? (130 - kc0) : 16;
        __syncthreads();
        for (int i = tid; i < cnt*32; i += 256)
            ((float4*)Wl)[i] = *(const float4*)&WG[(size_t)n*16640 + (size_t)kc0*128 + i*4];
        __syncthreads();
        for (int kk = 0; kk < cnt; kk++) {
            float4 a4 = *(float4*)&Zl[(kc0+kk)*64 + b0];
            float4 wz = *(float4*)&Wl[kk*128 + j0];
            float4 wr = *(float4*)&Wl[kk*128 + 64 + j0];
            float wza[4] = {wz.x,wz.y,wz.z,wz.w};
            float wra[4] = {wr.x,wr.y,wr.z,wr.w};
#pragma unroll
            for (int i = 0; i < 4; i++) {
                accz[i] = f4fma(accz[i], a4, wza[i]);
                accr[i] = f4fma(accr[i], a4, wra[i]);
            }
        }
    }
    const float* bg = BG + n*128;
#pragma unroll
    for (int i = 0; i < 4; i++) {
        int j = j0 + i;
        float4 z = sig4(accz[i], bg[j]);
        float4 r = sig4(accr[i], bg[64+j]);
        float4 h = *(const float4*)&XS[(size_t)n*JW2 + (1+j)*64 + b0];
        float4 zh; zh.x = z.x*h.x; zh.y = z.y*h.y; zh.z = z.z*h.z; zh.w = z.w*h.w;
        *(float4*)&CAND[(size_t)n*JW2 + (1+j)*64 + b0] = zh;
        *(float4*)&Rb[(size_t)n*4096 + j*64 + b0] = r;
    }
    if (tid < 16)
        ((float4*)(CAND + (size_t)n*JW2))[tid] = ((float4*)Zl)[tid];   // xt row
}

// ---------------- up: per-node GEMM (64 x 130)@(130 x 64) + tanh + h update ----------------
__global__ __launch_bounds__(256) void k_up(const float* __restrict__ CAND,
                                            const float* __restrict__ CG0,
                                            const float* __restrict__ CG1,
                                            int split,
                                            const float* __restrict__ WU,
                                            const float* __restrict__ BU,
                                            const float* __restrict__ Rb,
                                            float* __restrict__ XS,
                                            const float* __restrict__ src,
                                            int tnext, int hasNext) {
    int n = blockIdx.x, tid = threadIdx.x;
    __shared__ float Zl[130*64];
    __shared__ float Wl[16*64];
    {
        const float4* c4  = (const float4*)(CAND + (size_t)n*JW2);
        const float4* g04 = (const float4*)(CG0 + (size_t)n*JW2);
        const float4* g14 = (const float4*)(CG1 + (size_t)n*JW2);
        float4* zl4 = (float4*)Zl;
        for (int i = tid; i < 1040; i += 256) zl4[i] = c4[i];
        for (int i = tid; i < 1040; i += 256) {
            float4 v = g04[i];
            if (split) v = f4add(v, g14[i]);
            zl4[1040 + i] = v;
        }
    }
    int jt = tid & 15, bt = tid >> 4;
    int j0 = jt*4, b0 = bt*4;
    float4 acc[4];
#pragma unroll
    for (int i = 0; i < 4; i++) acc[i] = make_float4(0,0,0,0);

    for (int kc0 = 0; kc0 < 130; kc0 += 16) {
        int cnt = (130 - kc0 < 16) ? (130 - kc0) : 16;
        __syncthreads();
        for (int i = tid; i < cnt*16; i += 256)
            ((float4*)Wl)[i] = *(const float4*)&WU[(size_t)n*8320 + (size_t)kc0*64 + i*4];
        __syncthreads();
        for (int kk = 0; kk < cnt; kk++) {
            float4 a4 = *(float4*)&Zl[(kc0+kk)*64 + b0];
            float4 w4 = *(float4*)&Wl[kk*64 + j0];
            float wa[4] = {w4.x,w4.y,w4.z,w4.w};
#pragma unroll
            for (int i = 0; i < 4; i++) acc[i] = f4fma(acc[i], a4, wa[i]);
        }
    }
    const float* bu = BU + n*64;
#pragma unroll
    for (int i = 0; i < 4; i++) {
        int j = j0 + i;
        float4 hc = tanh4(acc[i], bu[j]);
        float4 r  = *(const float4*)&Rb[(size_t)n*4096 + j*64 + b0];
        size_t xi = (size_t)n*JW2 + (1+j)*64 + b0;
        float4 hold = *(const float4*)&XS[xi];
        float4 hn;
        hn.x = r.x*hold.x + (1.f-r.x)*hc.x;
        hn.y = r.y*hold.y + (1.f-r.y)*hc.y;
        hn.z = r.z*hold.z + (1.f-r.z)*hc.z;
        hn.w = r.w*hold.w + (1.f-r.w)*hc.w;
        *(float4*)&XS[xi] = hn;
    }
    __syncthreads();
    if (hasNext && tid < 64)
        XS[(size_t)n*JW2 + tid] = src[((size_t)tid*T_STEPS + tnext)*N_NODES + n];
}

// ---------------- head 1: OUT1 = h1.c1W + c1b ; SRC2 = src - (OUT1.c2W + c2b) ----------------
__global__ __launch_bounds__(256) void k_head1(const float* __restrict__ XS,
                                               const float* __restrict__ c1W,
                                               const float* __restrict__ c1b,
                                               const float* __restrict__ c2W,
                                               const float* __restrict__ c2b,
                                               const float* __restrict__ src,
                                               float* __restrict__ OUT1,
                                               float* __restrict__ SRC2) {
    int n = blockIdx.x, tid = threadIdx.x;
    __shared__ float Hl[64][65];
    __shared__ float w1[12][64];
    __shared__ float o1[64][13];
    for (int i = tid; i < 4096; i += 256) {
        int j = i >> 6, b = i & 63;
        Hl[b][j] = XS[(size_t)n*JW2 + 64 + i];
    }
    for (int i = tid; i < 768; i += 256) w1[i >> 6][i & 63] = c1W[i];
    __syncthreads();
    int b = tid & 63, cg = tid >> 6;
#pragma unroll
    for (int cc = 0; cc < 3; cc++) {
        int c = cg*3 + cc;
        float accv = c1b[c];
        for (int j = 0; j < 64; j++) accv += Hl[b][j]*w1[c][j];
        o1[b][c] = accv;
    }
    __syncthreads();
#pragma unroll
    for (int cc = 0; cc < 3; cc++) {
        int c = cg*3 + cc;
        float s1 = c2b[c];
#pragma unroll
        for (int j = 0; j < 12; j++) s1 += o1[b][j]*c2W[c*12 + j];
        size_t idx = ((size_t)b*12 + c)*1024 + n;
        OUT1[idx] = o1[b][c];
        SRC2[idx] = src[idx] - s1;
    }
}

// ---------------- head 2: out = OUT1 + h2.c3W + c3b ----------------
__global__ __launch_bounds__(256) void k_head2(const float* __restrict__ XS,
                                               const float* __restrict__ c3W,
                                               const float* __restrict__ c3b,
                                               const float* __restrict__ OUT1,
                                               float* __restrict__ out) {
    int n = blockIdx.x, tid = threadIdx.x;
    __shared__ float Hl[64][65];
    __shared__ float w3[12][64];
    for (int i = tid; i < 4096; i += 256) {
        int j = i >> 6, b = i & 63;
        Hl[b][j] = XS[(size_t)n*JW2 + 64 + i];
    }
    for (int i = tid; i < 768; i += 256) w3[i >> 6][i & 63] = c3W[i];
    __syncthreads();
    int b = tid & 63, cg = tid >> 6;
#pragma unroll
    for (int cc = 0; cc < 3; cc++) {
        int c = cg*3 + cc;
        float accv = c3b[c];
        for (int j = 0; j < 64; j++) accv += Hl[b][j]*w3[c][j];
        size_t idx = ((size_t)b*12 + c)*1024 + n;
        out[idx] = OUT1[idx] + accv;
    }
}

extern "C" void kernel_launch(void* const* d_in, const int* in_sizes, int n_in,
                              void* d_out, int out_size, void* d_ws, size_t ws_size,
                              hipStream_t stream) {
    const float* src  = (const float*)d_in[0];
    const float* E    = (const float*)d_in[1];
    const float* e1gW = (const float*)d_in[2];
    const float* e1gb = (const float*)d_in[3];
    const float* e1uW = (const float*)d_in[4];
    const float* e1ub = (const float*)d_in[5];
    const float* e2gW = (const float*)d_in[6];
    const float* e2gb = (const float*)d_in[7];
    const float* e2uW = (const float*)d_in[8];
    const float* e2ub = (const float*)d_in[9];
    const float* c1W  = (const float*)d_in[10];
    const float* c1b  = (const float*)d_in[11];
    const float* c2W  = (const float*)d_in[12];
    const float* c2b  = (const float*)d_in[13];
    const float* c3W  = (const float*)d_in[14];
    const float* c3b  = (const float*)d_in[15];

    float* ws = (float*)d_ws;
    float* A    = ws;                      // 1,048,576
    float* WG   = A    + 1048576;          // 17,039,360
    float* WU   = WG   + 17039360;         //  8,519,680
    float* BG   = WU   + 8519680;          //    131,072
    float* BU   = BG   + 131072;           //     65,536
    float* XS   = BU   + 65536;            //  4,325,376
    float* ZG0  = XS   + NELEM;            //  4,325,376
    float* CAND = ZG0  + NELEM;            //  4,325,376
    float* Rb   = CAND + NELEM;            //  4,194,304
    float* OUT1 = Rb   + 4194304;          //    786,432
    float* SRC2 = OUT1 + 786432;           //    786,432
    float* ZG1  = SRC2 + 786432;           //  4,325,376 (only if split fits)

    const size_t need_split = (size_t)(45547520 + NELEM) * 4;  // 199.5 MB
    int split = (ws_size >= need_split) ? 1 : 0;
    int KL = split ? 512 : 1024;
    dim3 ggrid(33, 8, split ? 2 : 1);
    const float* ZG1r = split ? ZG1 : ZG0;   // harmless when split==0

    k_supports<<<N_NODES, 256, 0, stream>>>(E, A);

    auto run_encoder = [&](const float* s, const float* gW, const float* gb,
                           const float* uW, const float* ub) {
        k_mix<<<dim3(65, 32), 256, 0, stream>>>(E, gW, WG, 16640);
        k_mix<<<dim3(33, 32), 256, 0, stream>>>(E, uW, WU, 8320);
        k_mix<<<dim3(1, 32),  256, 0, stream>>>(E, gb, BG, 128);
        k_mix<<<dim3(1, 32),  256, 0, stream>>>(E, ub, BU, 64);
        k_init_xs<<<NELEM/256, 256, 0, stream>>>(s, XS);
        for (int t = 0; t < T_STEPS; t++) {
            k_gemm<<<ggrid, 256, 0, stream>>>(A, XS, ZG0, KL);
            // note: split path writes halves at ZG0 and ZG0+offset; use ZG1 as half 2
            k_gate<<<N_NODES, 256, 0, stream>>>(XS, ZG0, ZG1r, split, WG, BG, CAND, Rb);
            k_gemm<<<ggrid, 256, 0, stream>>>(A, CAND, ZG0, KL);
            k_up<<<N_NODES, 256, 0, stream>>>(CAND, ZG0, ZG1r, split, WU, BU, Rb, XS, s,
                                              t + 1, (t + 1 < T_STEPS) ? 1 : 0);
        }
    };

    // K-split: block z writes into ZG0 + z*NELEM. ZG1 must be contiguous after... it is not,
    // so pass explicit base: we give k_gemm C=ZG0 and rely on blockIdx.z offset below.
    // (k_gemm uses C + z*... -- implemented via pointer arithmetic here instead:)
    // To keep k_gemm simple it writes C[blockIdx.z selected by caller]: we instead launch
    // with grid.z and index inside using KL*blockIdx.z for K and the SAME C... that would
    // collide. So when split, we launch two separate gemm calls, one per half.
    (void)ggrid;

    auto gemm_call = [&](const float* Xin, float* Cout) {
        if (split) {
            k_gemm<<<dim3(33, 8, 1), 256, 0, stream>>>(A, Xin, Cout, 512);
            k_gemm<<<dim3(33, 8, 1), 256, 0, stream>>>(A + 512, Xin + (size_t)512*JW2, ZG1, 512);
        } else {
            k_gemm<<<dim3(33, 8, 1), 256, 0, stream>>>(A, Xin, Cout, 1024);
        }
    };

    auto run_encoder2 = [&](const float* s, const float* gW, const float* gb,
                            const float* uW, const float* ub) {
        k_mix<<<dim3(65, 32), 256, 0, stream>>>(E, gW, WG, 16640);
        k_mix<<<dim3(33, 32), 256, 0, stream>>>(E, uW, WU, 8320);
        k_mix<<<dim3(1, 32),  256, 0, stream>>>(E, gb, BG, 128);
        k_mix<<<dim3(1, 32),  256, 0, stream>>>(E, ub, BU, 64);
        k_init_xs<<<NELEM/256, 256, 0, stream>>>(s, XS);
        for (int t = 0; t < T_STEPS; t++) {
            gemm_call(XS, ZG0);
            k_gate<<<N_NODES, 256, 0, stream>>>(XS, ZG0, ZG1r, split, WG, BG, CAND, Rb);
            gemm_call(CAND, ZG0);
            k_up<<<N_NODES, 256, 0, stream>>>(CAND, ZG0, ZG1r, split, WU, BU, Rb, XS, s,
                                              t + 1, (t + 1 < T_STEPS) ? 1 : 0);
        }
    };
    (void)run_encoder;

    run_encoder2(src, e1gW, e1gb, e1uW, e1ub);
    k_head1<<<N_NODES, 256, 0, stream>>>(XS, c1W, c1b, c2W, c2b, src, OUT1, SRC2);
    run_encoder2(SRC2, e2gW, e2gb, e2uW, e2ub);
    k_head2<<<N_NODES, 256, 0, stream>>>(XS, c3W, c3b, OUT1, (float*)d_out);
}

// Round 3
// 9961.320 us; speedup vs baseline: 5.7722x; 1.0714x over previous
//
#include <hip/hip_runtime.h>

#define N_NODES 1024
#define T_STEPS 12
#define JW2     4224          // padded column count = 33*128 (real 4160 = 65*64)
#define NELEM   (N_NODES*JW2) // 4,325,376

__device__ __forceinline__ float4 f4fma(float4 acc, float4 a, float s) {
    acc.x = fmaf(a.x, s, acc.x); acc.y = fmaf(a.y, s, acc.y);
    acc.z = fmaf(a.z, s, acc.z); acc.w = fmaf(a.w, s, acc.w);
    return acc;
}
__device__ __forceinline__ float4 sig4(float4 v, float b) {
    float4 r;
    r.x = 1.f/(1.f+expf(-(v.x+b))); r.y = 1.f/(1.f+expf(-(v.y+b)));
    r.z = 1.f/(1.f+expf(-(v.z+b))); r.w = 1.f/(1.f+expf(-(v.w+b)));
    return r;
}
__device__ __forceinline__ float4 tanh4(float4 v, float b) {
    float4 r;
    r.x = tanhf(v.x+b); r.y = tanhf(v.y+b);
    r.z = tanhf(v.z+b); r.w = tanhf(v.w+b);
    return r;
}

// ---------------- A = softmax(relu(E E^T), axis=1) ----------------
__global__ __launch_bounds__(256) void k_supports(const float* __restrict__ E,
                                                  float* __restrict__ A) {
    int n = blockIdx.x;
    int tid = threadIdx.x;
    __shared__ float en[16];
    __shared__ float red[256];
    if (tid < 16) en[tid] = E[n*16 + tid];
    __syncthreads();
    float s[4];
    float mx = -1e30f;
#pragma unroll
    for (int i = 0; i < 4; i++) {
        int m = tid + i*256;
        float acc = 0.f;
#pragma unroll
        for (int d = 0; d < 16; d++) acc += en[d]*E[m*16 + d];
        acc = fmaxf(acc, 0.f);
        s[i] = acc;
        mx = fmaxf(mx, acc);
    }
    red[tid] = mx; __syncthreads();
    for (int st = 128; st > 0; st >>= 1) {
        if (tid < st) red[tid] = fmaxf(red[tid], red[tid+st]);
        __syncthreads();
    }
    mx = red[0]; __syncthreads();
    float sum = 0.f;
#pragma unroll
    for (int i = 0; i < 4; i++) { s[i] = expf(s[i]-mx); sum += s[i]; }
    red[tid] = sum; __syncthreads();
    for (int st = 128; st > 0; st >>= 1) {
        if (tid < st) red[tid] += red[tid+st];
        __syncthreads();
    }
    float inv = 1.f / red[0];
#pragma unroll
    for (int i = 0; i < 4; i++) A[(size_t)n*1024 + tid + i*256] = s[i]*inv;
}

// ---------------- Wout[n, idx] = sum_d E[n,d] * Win[d, idx] ----------------
__global__ __launch_bounds__(256) void k_mix(const float* __restrict__ E,
                                             const float* __restrict__ Win,
                                             float* __restrict__ Wout, int SZ) {
    int idx = blockIdx.x*256 + threadIdx.x;
    if (idx >= SZ) return;
    float w[16];
#pragma unroll
    for (int d = 0; d < 16; d++) w[d] = Win[(size_t)d*SZ + idx];
    int n0 = blockIdx.y * 32;
    for (int n = n0; n < n0+32; n++) {
        float acc = 0.f;
#pragma unroll
        for (int d = 0; d < 16; d++) acc += E[n*16 + d]*w[d];
        Wout[(size_t)n*SZ + idx] = acc;
    }
}

// ---------------- XS init (c-major layout): XS[n][c*64+b], pads zeroed ----------------
__global__ __launch_bounds__(256) void k_init_xs(const float* __restrict__ src,
                                                 float* __restrict__ XS) {
    int i = blockIdx.x*256 + threadIdx.x;   // grid covers NELEM exactly
    int col = i % JW2;
    int n   = i / JW2;
    float v = 0.f;
    if (col < 64) v = src[((size_t)col*T_STEPS)*N_NODES + n];  // c==0 row: xt(b=col)
    XS[i] = v;
}

// ---------------- graph conv: C[n][col] = sum_m A[n][m] X[m][col] ----------------
// tile 64 rows x 128 cols, 256 threads, per-thread 8x4, K-chunk 32.
// grid (33, 16) = 528 blocks -> ~2 blocks/CU resident, 24 waves/CU.
__global__ __launch_bounds__(256) void k_gemm(const float* __restrict__ A,
                                              const float* __restrict__ X,
                                              float* __restrict__ C) {
    __shared__ float As[32][68];    // [kk][row] (transposed A tile)
    __shared__ float Xs[32][132];   // [kk][col]
    int tid = threadIdx.x;
    int tx = tid & 31, ty = tid >> 5;        // cols tx*4, rows ty*8
    int n0 = blockIdx.y * 64;
    int j0 = blockIdx.x * 128;
    int arow = tid & 63, aseg = tid >> 6;    // A stage: row, k-segment (8 wide)
    int xcol = (tid & 31) * 4, xk = tid >> 5; // X stage: 4 rows (xk+8q), 4 cols

    float4 acc[8];
#pragma unroll
    for (int i = 0; i < 8; i++) acc[i] = make_float4(0.f,0.f,0.f,0.f);

    for (int kc = 0; kc < 1024; kc += 32) {
        float4 av0 = *(const float4*)&A[(size_t)(n0+arow)*1024 + kc + aseg*8];
        float4 av1 = *(const float4*)&A[(size_t)(n0+arow)*1024 + kc + aseg*8 + 4];
        float4 xv[4];
#pragma unroll
        for (int q = 0; q < 4; q++)
            xv[q] = *(const float4*)&X[(size_t)(kc + xk + 8*q)*JW2 + j0 + xcol];
        __syncthreads();
        As[aseg*8+0][arow] = av0.x; As[aseg*8+1][arow] = av0.y;
        As[aseg*8+2][arow] = av0.z; As[aseg*8+3][arow] = av0.w;
        As[aseg*8+4][arow] = av1.x; As[aseg*8+5][arow] = av1.y;
        As[aseg*8+6][arow] = av1.z; As[aseg*8+7][arow] = av1.w;
#pragma unroll
        for (int q = 0; q < 4; q++)
            *(float4*)&Xs[xk + 8*q][xcol] = xv[q];
        __syncthreads();
#pragma unroll
        for (int kk = 0; kk < 32; kk++) {
            float4 a0 = *(float4*)&As[kk][ty*8];
            float4 a1 = *(float4*)&As[kk][ty*8+4];
            float4 b  = *(float4*)&Xs[kk][tx*4];
            acc[0] = f4fma(acc[0], b, a0.x); acc[1] = f4fma(acc[1], b, a0.y);
            acc[2] = f4fma(acc[2], b, a0.z); acc[3] = f4fma(acc[3], b, a0.w);
            acc[4] = f4fma(acc[4], b, a1.x); acc[5] = f4fma(acc[5], b, a1.y);
            acc[6] = f4fma(acc[6], b, a1.z); acc[7] = f4fma(acc[7], b, a1.w);
        }
        __syncthreads();
    }
#pragma unroll
    for (int i = 0; i < 8; i++)
        *(float4*)&C[(size_t)(n0 + ty*8 + i)*JW2 + j0 + tx*4] = acc[i];
}

// ---------------- gate: per-node GEMM (64b x 130kc)@(130 x 128) + sigmoid ----------------
// Zl rows 0..64 = xs (xt;h), rows 65..129 = A@xs. Writes CAND=(xt; z*h), Rb=r.
__global__ __launch_bounds__(256) void k_gate(const float* __restrict__ XS,
                                              const float* __restrict__ ZG,
                                              const float* __restrict__ WG,
                                              const float* __restrict__ BG,
                                              float* __restrict__ CAND,
                                              float* __restrict__ Rb) {
    int n = blockIdx.x, tid = threadIdx.x;
    __shared__ float Zl[130*64];
    __shared__ float Wl[16*128];
    {
        const float4* xs4 = (const float4*)(XS + (size_t)n*JW2);
        const float4* z4  = (const float4*)(ZG + (size_t)n*JW2);
        float4* zl4 = (float4*)Zl;
        for (int i = tid; i < 1040; i += 256) zl4[i] = xs4[i];
        for (int i = tid; i < 1040; i += 256) zl4[1040 + i] = z4[i];
    }
    int jt = tid & 15, bt = tid >> 4;
    int j0 = jt*4, b0 = bt*4;
    float4 accz[4], accr[4];
#pragma unroll
    for (int i = 0; i < 4; i++) { accz[i] = make_float4(0,0,0,0); accr[i] = make_float4(0,0,0,0); }

    for (int kc0 = 0; kc0 < 130; kc0 += 16) {
        int cnt = (130 - kc0 < 16) ? (130 - kc0) : 16;
        __syncthreads();
        for (int i = tid; i < cnt*32; i += 256)
            ((float4*)Wl)[i] = *(const float4*)&WG[(size_t)n*16640 + (size_t)kc0*128 + i*4];
        __syncthreads();
        for (int kk = 0; kk < cnt; kk++) {
            float4 a4 = *(float4*)&Zl[(kc0+kk)*64 + b0];
            float4 wz = *(float4*)&Wl[kk*128 + j0];
            float4 wr = *(float4*)&Wl[kk*128 + 64 + j0];
            float wza[4] = {wz.x,wz.y,wz.z,wz.w};
            float wra[4] = {wr.x,wr.y,wr.z,wr.w};
#pragma unroll
            for (int i = 0; i < 4; i++) {
                accz[i] = f4fma(accz[i], a4, wza[i]);
                accr[i] = f4fma(accr[i], a4, wra[i]);
            }
        }
    }
    const float* bg = BG + n*128;
#pragma unroll
    for (int i = 0; i < 4; i++) {
        int j = j0 + i;
        float4 z = sig4(accz[i], bg[j]);
        float4 r = sig4(accr[i], bg[64+j]);
        float4 h = *(const float4*)&XS[(size_t)n*JW2 + (1+j)*64 + b0];
        float4 zh; zh.x = z.x*h.x; zh.y = z.y*h.y; zh.z = z.z*h.z; zh.w = z.w*h.w;
        *(float4*)&CAND[(size_t)n*JW2 + (1+j)*64 + b0] = zh;
        *(float4*)&Rb[(size_t)n*4096 + j*64 + b0] = r;
    }
    if (tid < 16)
        ((float4*)(CAND + (size_t)n*JW2))[tid] = ((float4*)Zl)[tid];   // xt row
}

// ---------------- up: per-node GEMM (64 x 130)@(130 x 64) + tanh + h update ----------------
__global__ __launch_bounds__(256) void k_up(const float* __restrict__ CAND,
                                            const float* __restrict__ CG,
                                            const float* __restrict__ WU,
                                            const float* __restrict__ BU,
                                            const float* __restrict__ Rb,
                                            float* __restrict__ XS,
                                            const float* __restrict__ src,
                                            int tnext, int hasNext) {
    int n = blockIdx.x, tid = threadIdx.x;
    __shared__ float Zl[130*64];
    __shared__ float Wl[16*64];
    {
        const float4* c4 = (const float4*)(CAND + (size_t)n*JW2);
        const float4* g4 = (const float4*)(CG + (size_t)n*JW2);
        float4* zl4 = (float4*)Zl;
        for (int i = tid; i < 1040; i += 256) zl4[i] = c4[i];
        for (int i = tid; i < 1040; i += 256) zl4[1040 + i] = g4[i];
    }
    int jt = tid & 15, bt = tid >> 4;
    int j0 = jt*4, b0 = bt*4;
    float4 acc[4];
#pragma unroll
    for (int i = 0; i < 4; i++) acc[i] = make_float4(0,0,0,0);

    for (int kc0 = 0; kc0 < 130; kc0 += 16) {
        int cnt = (130 - kc0 < 16) ? (130 - kc0) : 16;
        __syncthreads();
        for (int i = tid; i < cnt*16; i += 256)
            ((float4*)Wl)[i] = *(const float4*)&WU[(size_t)n*8320 + (size_t)kc0*64 + i*4];
        __syncthreads();
        for (int kk = 0; kk < cnt; kk++) {
            float4 a4 = *(float4*)&Zl[(kc0+kk)*64 + b0];
            float4 w4 = *(float4*)&Wl[kk*64 + j0];
            float wa[4] = {w4.x,w4.y,w4.z,w4.w};
#pragma unroll
            for (int i = 0; i < 4; i++) acc[i] = f4fma(acc[i], a4, wa[i]);
        }
    }
    const float* bu = BU + n*64;
#pragma unroll
    for (int i = 0; i < 4; i++) {
        int j = j0 + i;
        float4 hc = tanh4(acc[i], bu[j]);
        float4 r  = *(const float4*)&Rb[(size_t)n*4096 + j*64 + b0];
        size_t xi = (size_t)n*JW2 + (1+j)*64 + b0;
        float4 hold = *(const float4*)&XS[xi];
        float4 hn;
        hn.x = r.x*hold.x + (1.f-r.x)*hc.x;
        hn.y = r.y*hold.y + (1.f-r.y)*hc.y;
        hn.z = r.z*hold.z + (1.f-r.z)*hc.z;
        hn.w = r.w*hold.w + (1.f-r.w)*hc.w;
        *(float4*)&XS[xi] = hn;
    }
    __syncthreads();
    if (hasNext && tid < 64)
        XS[(size_t)n*JW2 + tid] = src[((size_t)tid*T_STEPS + tnext)*N_NODES + n];
}

// ---------------- head 1: OUT1 = h1.c1W + c1b ; SRC2 = src - (OUT1.c2W + c2b) ----------------
__global__ __launch_bounds__(256) void k_head1(const float* __restrict__ XS,
                                               const float* __restrict__ c1W,
                                               const float* __restrict__ c1b,
                                               const float* __restrict__ c2W,
                                               const float* __restrict__ c2b,
                                               const float* __restrict__ src,
                                               float* __restrict__ OUT1,
                                               float* __restrict__ SRC2) {
    int n = blockIdx.x, tid = threadIdx.x;
    __shared__ float Hl[64][65];
    __shared__ float w1[12][64];
    __shared__ float o1[64][13];
    for (int i = tid; i < 4096; i += 256) {
        int j = i >> 6, b = i & 63;
        Hl[b][j] = XS[(size_t)n*JW2 + 64 + i];
    }
    for (int i = tid; i < 768; i += 256) w1[i >> 6][i & 63] = c1W[i];
    __syncthreads();
    int b = tid & 63, cg = tid >> 6;
#pragma unroll
    for (int cc = 0; cc < 3; cc++) {
        int c = cg*3 + cc;
        float accv = c1b[c];
        for (int j = 0; j < 64; j++) accv += Hl[b][j]*w1[c][j];
        o1[b][c] = accv;
    }
    __syncthreads();
#pragma unroll
    for (int cc = 0; cc < 3; cc++) {
        int c = cg*3 + cc;
        float s1 = c2b[c];
#pragma unroll
        for (int j = 0; j < 12; j++) s1 += o1[b][j]*c2W[c*12 + j];
        size_t idx = ((size_t)b*12 + c)*1024 + n;
        OUT1[idx] = o1[b][c];
        SRC2[idx] = src[idx] - s1;
    }
}

// ---------------- head 2: out = OUT1 + h2.c3W + c3b ----------------
__global__ __launch_bounds__(256) void k_head2(const float* __restrict__ XS,
                                               const float* __restrict__ c3W,
                                               const float* __restrict__ c3b,
                                               const float* __restrict__ OUT1,
                                               float* __restrict__ out) {
    int n = blockIdx.x, tid = threadIdx.x;
    __shared__ float Hl[64][65];
    __shared__ float w3[12][64];
    for (int i = tid; i < 4096; i += 256) {
        int j = i >> 6, b = i & 63;
        Hl[b][j] = XS[(size_t)n*JW2 + 64 + i];
    }
    for (int i = tid; i < 768; i += 256) w3[i >> 6][i & 63] = c3W[i];
    __syncthreads();
    int b = tid & 63, cg = tid >> 6;
#pragma unroll
    for (int cc = 0; cc < 3; cc++) {
        int c = cg*3 + cc;
        float accv = c3b[c];
        for (int j = 0; j < 64; j++) accv += Hl[b][j]*w3[c][j];
        size_t idx = ((size_t)b*12 + c)*1024 + n;
        out[idx] = OUT1[idx] + accv;
    }
}

extern "C" void kernel_launch(void* const* d_in, const int* in_sizes, int n_in,
                              void* d_out, int out_size, void* d_ws, size_t ws_size,
                              hipStream_t stream) {
    const float* src  = (const float*)d_in[0];
    const float* E    = (const float*)d_in[1];
    const float* e1gW = (const float*)d_in[2];
    const float* e1gb = (const float*)d_in[3];
    const float* e1uW = (const float*)d_in[4];
    const float* e1ub = (const float*)d_in[5];
    const float* e2gW = (const float*)d_in[6];
    const float* e2gb = (const float*)d_in[7];
    const float* e2uW = (const float*)d_in[8];
    const float* e2ub = (const float*)d_in[9];
    const float* c1W  = (const float*)d_in[10];
    const float* c1b  = (const float*)d_in[11];
    const float* c2W  = (const float*)d_in[12];
    const float* c2b  = (const float*)d_in[13];
    const float* c3W  = (const float*)d_in[14];
    const float* c3b  = (const float*)d_in[15];

    float* ws = (float*)d_ws;
    float* A    = ws;                      // 1,048,576
    float* WG   = A    + 1048576;          // 17,039,360
    float* WU   = WG   + 17039360;         //  8,519,680
    float* BG   = WU   + 8519680;          //    131,072
    float* BU   = BG   + 131072;           //     65,536
    float* XS   = BU   + 65536;            //  4,325,376
    float* ZG   = XS   + NELEM;            //  4,325,376
    float* CAND = ZG   + NELEM;            //  4,325,376
    float* Rb   = CAND + NELEM;            //  4,194,304
    float* OUT1 = Rb   + 4194304;          //    786,432
    float* SRC2 = OUT1 + 786432;           //    786,432  -> ~182 MB total

    k_supports<<<N_NODES, 256, 0, stream>>>(E, A);

    auto run_encoder = [&](const float* s, const float* gW, const float* gb,
                           const float* uW, const float* ub) {
        k_mix<<<dim3(65, 32), 256, 0, stream>>>(E, gW, WG, 16640);
        k_mix<<<dim3(33, 32), 256, 0, stream>>>(E, uW, WU, 8320);
        k_mix<<<dim3(1, 32),  256, 0, stream>>>(E, gb, BG, 128);
        k_mix<<<dim3(1, 32),  256, 0, stream>>>(E, ub, BU, 64);
        k_init_xs<<<NELEM/256, 256, 0, stream>>>(s, XS);
        for (int t = 0; t < T_STEPS; t++) {
            k_gemm<<<dim3(33, 16), 256, 0, stream>>>(A, XS, ZG);
            k_gate<<<N_NODES, 256, 0, stream>>>(XS, ZG, WG, BG, CAND, Rb);
            k_gemm<<<dim3(33, 16), 256, 0, stream>>>(A, CAND, ZG);
            k_up<<<N_NODES, 256, 0, stream>>>(CAND, ZG, WU, BU, Rb, XS, s,
                                              t + 1, (t + 1 < T_STEPS) ? 1 : 0);
        }
    };

    run_encoder(src, e1gW, e1gb, e1uW, e1ub);
    k_head1<<<N_NODES, 256, 0, stream>>>(XS, c1W, c1b, c2W, c2b, src, OUT1, SRC2);
    run_encoder(SRC2, e2gW, e2gb, e2uW, e2ub);
    k_head2<<<N_NODES, 256, 0, stream>>>(XS, c3W, c3b, OUT1, (float*)d_out);
}

// Round 4
// 8575.686 us; speedup vs baseline: 6.7049x; 1.1616x over previous
//
#include <hip/hip_runtime.h>

#define N_NODES 1024
#define T_STEPS 12
#define JW2     4224          // padded column count = 33*128 (real 4160 = 65*64)
#define NELEM   (N_NODES*JW2) // 4,325,376

__device__ __forceinline__ float4 f4fma(float4 acc, float4 a, float s) {
    acc.x = fmaf(a.x, s, acc.x); acc.y = fmaf(a.y, s, acc.y);
    acc.z = fmaf(a.z, s, acc.z); acc.w = fmaf(a.w, s, acc.w);
    return acc;
}
__device__ __forceinline__ float4 sig4(float4 v, float b) {
    float4 r;
    r.x = 1.f/(1.f+expf(-(v.x+b))); r.y = 1.f/(1.f+expf(-(v.y+b)));
    r.z = 1.f/(1.f+expf(-(v.z+b))); r.w = 1.f/(1.f+expf(-(v.w+b)));
    return r;
}
__device__ __forceinline__ float4 tanh4(float4 v, float b) {
    float4 r;
    r.x = tanhf(v.x+b); r.y = tanhf(v.y+b);
    r.z = tanhf(v.z+b); r.w = tanhf(v.w+b);
    return r;
}

// ---------------- A = softmax(relu(E E^T), axis=1) ----------------
__global__ __launch_bounds__(256) void k_supports(const float* __restrict__ E,
                                                  float* __restrict__ A) {
    int n = blockIdx.x;
    int tid = threadIdx.x;
    __shared__ float en[16];
    __shared__ float red[256];
    if (tid < 16) en[tid] = E[n*16 + tid];
    __syncthreads();
    float s[4];
    float mx = -1e30f;
#pragma unroll
    for (int i = 0; i < 4; i++) {
        int m = tid + i*256;
        float acc = 0.f;
#pragma unroll
        for (int d = 0; d < 16; d++) acc += en[d]*E[m*16 + d];
        acc = fmaxf(acc, 0.f);
        s[i] = acc;
        mx = fmaxf(mx, acc);
    }
    red[tid] = mx; __syncthreads();
    for (int st = 128; st > 0; st >>= 1) {
        if (tid < st) red[tid] = fmaxf(red[tid], red[tid+st]);
        __syncthreads();
    }
    mx = red[0]; __syncthreads();
    float sum = 0.f;
#pragma unroll
    for (int i = 0; i < 4; i++) { s[i] = expf(s[i]-mx); sum += s[i]; }
    red[tid] = sum; __syncthreads();
    for (int st = 128; st > 0; st >>= 1) {
        if (tid < st) red[tid] += red[tid+st];
        __syncthreads();
    }
    float inv = 1.f / red[0];
#pragma unroll
    for (int i = 0; i < 4; i++) A[(size_t)n*1024 + tid + i*256] = s[i]*inv;
}

// ---------------- Wout[n, idx] = sum_d E[n,d] * Win[d, idx] ----------------
__global__ __launch_bounds__(256) void k_mix(const float* __restrict__ E,
                                             const float* __restrict__ Win,
                                             float* __restrict__ Wout, int SZ) {
    int idx = blockIdx.x*256 + threadIdx.x;
    if (idx >= SZ) return;
    float w[16];
#pragma unroll
    for (int d = 0; d < 16; d++) w[d] = Win[(size_t)d*SZ + idx];
    int n0 = blockIdx.y * 32;
    for (int n = n0; n < n0+32; n++) {
        float acc = 0.f;
#pragma unroll
        for (int d = 0; d < 16; d++) acc += E[n*16 + d]*w[d];
        Wout[(size_t)n*SZ + idx] = acc;
    }
}

// ---------------- XS init (c-major layout): XS[n][c*64+b], pads zeroed ----------------
__global__ __launch_bounds__(256) void k_init_xs(const float* __restrict__ src,
                                                 float* __restrict__ XS) {
    int i = blockIdx.x*256 + threadIdx.x;   // grid covers NELEM exactly
    int col = i % JW2;
    int n   = i / JW2;
    float v = 0.f;
    if (col < 64) v = src[((size_t)col*T_STEPS)*N_NODES + n];  // c==0 row: xt(b=col)
    XS[i] = v;
}

// ---------------- graph conv: C[n][col] = sum_m A[n][m] X[m][col] ----------------
// tile 64x64, 256 threads, per-thread 4x4, K-chunk 32.
// grid 1056 blocks (66 j-tiles x 16 n-tiles), XCD-swizzled:
//   xcd = g%8 owns 2 row-panels; consecutive ranks alternate panels sharing X tile.
__global__ __launch_bounds__(256) void k_gemm(const float* __restrict__ A,
                                              const float* __restrict__ X,
                                              float* __restrict__ C) {
    __shared__ float As[32][68];    // [kk][row] (transposed A tile)
    __shared__ float Xs[32][68];    // [kk][col]
    int g = blockIdx.x;
    int xcd  = g & 7;
    int rank = g >> 3;              // 0..131
    int bx = rank >> 1;             // 0..65
    int by = xcd*2 + (rank & 1);    // 0..15
    int n0 = by * 64;
    int j0 = bx * 64;

    int tid = threadIdx.x;
    int tx = tid & 15, ty = tid >> 4;          // col tx*4, row ty*4
    int arow = tid & 63, aseg = tid >> 6;      // A stage: row, 8-wide k segment
    int xk = tid >> 4, xcol = (tid & 15) * 4;  // X stage: rows xk, xk+16

    float4 acc[4];
#pragma unroll
    for (int i = 0; i < 4; i++) acc[i] = make_float4(0.f,0.f,0.f,0.f);

    for (int kc = 0; kc < 1024; kc += 32) {
        float4 av0 = *(const float4*)&A[(size_t)(n0+arow)*1024 + kc + aseg*8];
        float4 av1 = *(const float4*)&A[(size_t)(n0+arow)*1024 + kc + aseg*8 + 4];
        float4 xv0 = *(const float4*)&X[(size_t)(kc + xk)*JW2 + j0 + xcol];
        float4 xv1 = *(const float4*)&X[(size_t)(kc + xk + 16)*JW2 + j0 + xcol];
        __syncthreads();
        As[aseg*8+0][arow] = av0.x; As[aseg*8+1][arow] = av0.y;
        As[aseg*8+2][arow] = av0.z; As[aseg*8+3][arow] = av0.w;
        As[aseg*8+4][arow] = av1.x; As[aseg*8+5][arow] = av1.y;
        As[aseg*8+6][arow] = av1.z; As[aseg*8+7][arow] = av1.w;
        *(float4*)&Xs[xk][xcol]      = xv0;
        *(float4*)&Xs[xk + 16][xcol] = xv1;
        __syncthreads();
#pragma unroll
        for (int kk = 0; kk < 32; kk++) {
            float4 a = *(float4*)&As[kk][ty*4];
            float4 b = *(float4*)&Xs[kk][tx*4];
            acc[0] = f4fma(acc[0], b, a.x);
            acc[1] = f4fma(acc[1], b, a.y);
            acc[2] = f4fma(acc[2], b, a.z);
            acc[3] = f4fma(acc[3], b, a.w);
        }
    }
#pragma unroll
    for (int i = 0; i < 4; i++)
        *(float4*)&C[(size_t)(n0 + ty*4 + i)*JW2 + j0 + tx*4] = acc[i];
}

// ---------------- gate: per-node GEMM (64b x 130kc)@(130 x 128) + sigmoid ----------------
// W staged in 5 chunks {32,32,32,32,2} with register prefetch (issue-early/write-late).
__global__ __launch_bounds__(256) void k_gate(const float* __restrict__ XS,
                                              const float* __restrict__ ZG,
                                              const float* __restrict__ WG,
                                              const float* __restrict__ BG,
                                              float* __restrict__ CAND,
                                              float* __restrict__ Rb) {
    int n = blockIdx.x, tid = threadIdx.x;
    __shared__ float Zl[130*64];    // 33.3 KB
    __shared__ float Wl[32*128];    // 16 KB
    {
        const float4* xs4 = (const float4*)(XS + (size_t)n*JW2);
        const float4* z4  = (const float4*)(ZG + (size_t)n*JW2);
        float4* zl4 = (float4*)Zl;
        for (int i = tid; i < 1040; i += 256) zl4[i] = xs4[i];
        for (int i = tid; i < 1040; i += 256) zl4[1040 + i] = z4[i];
    }
    const float4* wg4 = (const float4*)(WG + (size_t)n*16640);
    float4 wreg0 = wg4[tid];
    float4 wreg1 = wg4[tid + 256];
    float4 wreg2 = wg4[tid + 512];
    float4 wreg3 = wg4[tid + 768];
    float wtail = 0.f;

    int jt = tid & 15, bt = tid >> 4;
    int j0 = jt*4, b0 = bt*4;
    float4 accz[4], accr[4];
#pragma unroll
    for (int i = 0; i < 4; i++) { accz[i] = make_float4(0,0,0,0); accr[i] = make_float4(0,0,0,0); }

    for (int c = 0; c < 5; c++) {
        int kc0 = c*32;
        int cnt = (c == 4) ? 2 : 32;
        __syncthreads();
        if (c < 4) {
            float4* wl4 = (float4*)Wl;
            wl4[tid]       = wreg0;
            wl4[tid + 256] = wreg1;
            wl4[tid + 512] = wreg2;
            wl4[tid + 768] = wreg3;
            if (c < 3) {
                wreg0 = wg4[(c+1)*1024 + tid];
                wreg1 = wg4[(c+1)*1024 + tid + 256];
                wreg2 = wg4[(c+1)*1024 + tid + 512];
                wreg3 = wg4[(c+1)*1024 + tid + 768];
            } else {
                wtail = WG[(size_t)n*16640 + 16384 + tid];   // kc 128,129
            }
        } else {
            Wl[tid] = wtail;
        }
        __syncthreads();
        for (int kk = 0; kk < cnt; kk++) {
            float4 a4 = *(float4*)&Zl[(kc0+kk)*64 + b0];
            float4 wz = *(float4*)&Wl[kk*128 + j0];
            float4 wr = *(float4*)&Wl[kk*128 + 64 + j0];
            float wza[4] = {wz.x,wz.y,wz.z,wz.w};
            float wra[4] = {wr.x,wr.y,wr.z,wr.w};
#pragma unroll
            for (int i = 0; i < 4; i++) {
                accz[i] = f4fma(accz[i], a4, wza[i]);
                accr[i] = f4fma(accr[i], a4, wra[i]);
            }
        }
    }
    const float* bg = BG + n*128;
#pragma unroll
    for (int i = 0; i < 4; i++) {
        int j = j0 + i;
        float4 z = sig4(accz[i], bg[j]);
        float4 r = sig4(accr[i], bg[64+j]);
        float4 h = *(const float4*)&XS[(size_t)n*JW2 + (1+j)*64 + b0];
        float4 zh; zh.x = z.x*h.x; zh.y = z.y*h.y; zh.z = z.z*h.z; zh.w = z.w*h.w;
        *(float4*)&CAND[(size_t)n*JW2 + (1+j)*64 + b0] = zh;
        *(float4*)&Rb[(size_t)n*4096 + j*64 + b0] = r;
    }
    if (tid < 16)
        ((float4*)(CAND + (size_t)n*JW2))[tid] = ((float4*)Zl)[tid];   // xt row
}

// ---------------- up: per-node GEMM (64 x 130)@(130 x 64) + tanh + h update ----------------
__global__ __launch_bounds__(256) void k_up(const float* __restrict__ CAND,
                                            const float* __restrict__ CG,
                                            const float* __restrict__ WU,
                                            const float* __restrict__ BU,
                                            const float* __restrict__ Rb,
                                            float* __restrict__ XS,
                                            const float* __restrict__ src,
                                            int tnext, int hasNext) {
    int n = blockIdx.x, tid = threadIdx.x;
    __shared__ float Zl[130*64];    // 33.3 KB
    __shared__ float Wl[32*64];     // 8 KB
    {
        const float4* c4 = (const float4*)(CAND + (size_t)n*JW2);
        const float4* g4 = (const float4*)(CG + (size_t)n*JW2);
        float4* zl4 = (float4*)Zl;
        for (int i = tid; i < 1040; i += 256) zl4[i] = c4[i];
        for (int i = tid; i < 1040; i += 256) zl4[1040 + i] = g4[i];
    }
    const float4* wu4 = (const float4*)(WU + (size_t)n*8320);
    float4 wreg0 = wu4[tid];
    float4 wreg1 = wu4[tid + 256];
    float wtail = 0.f;

    int jt = tid & 15, bt = tid >> 4;
    int j0 = jt*4, b0 = bt*4;
    float4 acc[4];
#pragma unroll
    for (int i = 0; i < 4; i++) acc[i] = make_float4(0,0,0,0);

    for (int c = 0; c < 5; c++) {
        int kc0 = c*32;
        int cnt = (c == 4) ? 2 : 32;
        __syncthreads();
        if (c < 4) {
            float4* wl4 = (float4*)Wl;
            wl4[tid]       = wreg0;
            wl4[tid + 256] = wreg1;
            if (c < 3) {
                wreg0 = wu4[(c+1)*512 + tid];
                wreg1 = wu4[(c+1)*512 + tid + 256];
            } else if (tid < 128) {
                wtail = WU[(size_t)n*8320 + 8192 + tid];     // kc 128,129
            }
        } else {
            if (tid < 128) Wl[tid] = wtail;
        }
        __syncthreads();
        for (int kk = 0; kk < cnt; kk++) {
            float4 a4 = *(float4*)&Zl[(kc0+kk)*64 + b0];
            float4 w4 = *(float4*)&Wl[kk*64 + j0];
            float wa[4] = {w4.x,w4.y,w4.z,w4.w};
#pragma unroll
            for (int i = 0; i < 4; i++) acc[i] = f4fma(acc[i], a4, wa[i]);
        }
    }
    const float* bu = BU + n*64;
#pragma unroll
    for (int i = 0; i < 4; i++) {
        int j = j0 + i;
        float4 hc = tanh4(acc[i], bu[j]);
        float4 r  = *(const float4*)&Rb[(size_t)n*4096 + j*64 + b0];
        size_t xi = (size_t)n*JW2 + (1+j)*64 + b0;
        float4 hold = *(const float4*)&XS[xi];
        float4 hn;
        hn.x = r.x*hold.x + (1.f-r.x)*hc.x;
        hn.y = r.y*hold.y + (1.f-r.y)*hc.y;
        hn.z = r.z*hold.z + (1.f-r.z)*hc.z;
        hn.w = r.w*hold.w + (1.f-r.w)*hc.w;
        *(float4*)&XS[xi] = hn;
    }
    __syncthreads();
    if (hasNext && tid < 64)
        XS[(size_t)n*JW2 + tid] = src[((size_t)tid*T_STEPS + tnext)*N_NODES + n];
}

// ---------------- head 1: OUT1 = h1.c1W + c1b ; SRC2 = src - (OUT1.c2W + c2b) ----------------
__global__ __launch_bounds__(256) void k_head1(const float* __restrict__ XS,
                                               const float* __restrict__ c1W,
                                               const float* __restrict__ c1b,
                                               const float* __restrict__ c2W,
                                               const float* __restrict__ c2b,
                                               const float* __restrict__ src,
                                               float* __restrict__ OUT1,
                                               float* __restrict__ SRC2) {
    int n = blockIdx.x, tid = threadIdx.x;
    __shared__ float Hl[64][65];
    __shared__ float w1[12][64];
    __shared__ float o1[64][13];
    for (int i = tid; i < 4096; i += 256) {
        int j = i >> 6, b = i & 63;
        Hl[b][j] = XS[(size_t)n*JW2 + 64 + i];
    }
    for (int i = tid; i < 768; i += 256) w1[i >> 6][i & 63] = c1W[i];
    __syncthreads();
    int b = tid & 63, cg = tid >> 6;
#pragma unroll
    for (int cc = 0; cc < 3; cc++) {
        int c = cg*3 + cc;
        float accv = c1b[c];
        for (int j = 0; j < 64; j++) accv += Hl[b][j]*w1[c][j];
        o1[b][c] = accv;
    }
    __syncthreads();
#pragma unroll
    for (int cc = 0; cc < 3; cc++) {
        int c = cg*3 + cc;
        float s1 = c2b[c];
#pragma unroll
        for (int j = 0; j < 12; j++) s1 += o1[b][j]*c2W[c*12 + j];
        size_t idx = ((size_t)b*12 + c)*1024 + n;
        OUT1[idx] = o1[b][c];
        SRC2[idx] = src[idx] - s1;
    }
}

// ---------------- head 2: out = OUT1 + h2.c3W + c3b ----------------
__global__ __launch_bounds__(256) void k_head2(const float* __restrict__ XS,
                                               const float* __restrict__ c3W,
                                               const float* __restrict__ c3b,
                                               const float* __restrict__ OUT1,
                                               float* __restrict__ out) {
    int n = blockIdx.x, tid = threadIdx.x;
    __shared__ float Hl[64][65];
    __shared__ float w3[12][64];
    for (int i = tid; i < 4096; i += 256) {
        int j = i >> 6, b = i & 63;
        Hl[b][j] = XS[(size_t)n*JW2 + 64 + i];
    }
    for (int i = tid; i < 768; i += 256) w3[i >> 6][i & 63] = c3W[i];
    __syncthreads();
    int b = tid & 63, cg = tid >> 6;
#pragma unroll
    for (int cc = 0; cc < 3; cc++) {
        int c = cg*3 + cc;
        float accv = c3b[c];
        for (int j = 0; j < 64; j++) accv += Hl[b][j]*w3[c][j];
        size_t idx = ((size_t)b*12 + c)*1024 + n;
        out[idx] = OUT1[idx] + accv;
    }
}

extern "C" void kernel_launch(void* const* d_in, const int* in_sizes, int n_in,
                              void* d_out, int out_size, void* d_ws, size_t ws_size,
                              hipStream_t stream) {
    const float* src  = (const float*)d_in[0];
    const float* E    = (const float*)d_in[1];
    const float* e1gW = (const float*)d_in[2];
    const float* e1gb = (const float*)d_in[3];
    const float* e1uW = (const float*)d_in[4];
    const float* e1ub = (const float*)d_in[5];
    const float* e2gW = (const float*)d_in[6];
    const float* e2gb = (const float*)d_in[7];
    const float* e2uW = (const float*)d_in[8];
    const float* e2ub = (const float*)d_in[9];
    const float* c1W  = (const float*)d_in[10];
    const float* c1b  = (const float*)d_in[11];
    const float* c2W  = (const float*)d_in[12];
    const float* c2b  = (const float*)d_in[13];
    const float* c3W  = (const float*)d_in[14];
    const float* c3b  = (const float*)d_in[15];

    float* ws = (float*)d_ws;
    float* A    = ws;                      // 1,048,576
    float* WG   = A    + 1048576;          // 17,039,360
    float* WU   = WG   + 17039360;         //  8,519,680
    float* BG   = WU   + 8519680;          //    131,072
    float* BU   = BG   + 131072;           //     65,536
    float* XS   = BU   + 65536;            //  4,325,376
    float* ZG   = XS   + NELEM;            //  4,325,376
    float* CAND = ZG   + NELEM;            //  4,325,376
    float* Rb   = CAND + NELEM;            //  4,194,304
    float* OUT1 = Rb   + 4194304;          //    786,432
    float* SRC2 = OUT1 + 786432;           //    786,432  -> ~182 MB total

    k_supports<<<N_NODES, 256, 0, stream>>>(E, A);

    auto run_encoder = [&](const float* s, const float* gW, const float* gb,
                           const float* uW, const float* ub) {
        k_mix<<<dim3(65, 32), 256, 0, stream>>>(E, gW, WG, 16640);
        k_mix<<<dim3(33, 32), 256, 0, stream>>>(E, uW, WU, 8320);
        k_mix<<<dim3(1, 32),  256, 0, stream>>>(E, gb, BG, 128);
        k_mix<<<dim3(1, 32),  256, 0, stream>>>(E, ub, BU, 64);
        k_init_xs<<<NELEM/256, 256, 0, stream>>>(s, XS);
        for (int t = 0; t < T_STEPS; t++) {
            k_gemm<<<1056, 256, 0, stream>>>(A, XS, ZG);
            k_gate<<<N_NODES, 256, 0, stream>>>(XS, ZG, WG, BG, CAND, Rb);
            k_gemm<<<1056, 256, 0, stream>>>(A, CAND, ZG);
            k_up<<<N_NODES, 256, 0, stream>>>(CAND, ZG, WU, BU, Rb, XS, s,
                                              t + 1, (t + 1 < T_STEPS) ? 1 : 0);
        }
    };

    run_encoder(src, e1gW, e1gb, e1uW, e1ub);
    k_head1<<<N_NODES, 256, 0, stream>>>(XS, c1W, c1b, c2W, c2b, src, OUT1, SRC2);
    run_encoder(SRC2, e2gW, e2gb, e2uW, e2ub);
    k_head2<<<N_NODES, 256, 0, stream>>>(XS, c3W, c3b, OUT1, (float*)d_out);
}